// Round 7
// baseline (501.834 us; speedup 1.0000x reference)
//
#include <hip/hip_runtime.h>
#include <hip/hip_bf16.h>
#include <stdint.h>

typedef __bf16 bf16_t;
typedef __bf16 bf16x8 __attribute__((ext_vector_type(8)));
typedef float f32x4 __attribute__((ext_vector_type(4)));

#define Edim 2048
#define Cdim 64
#define Fdim 18
#define Pdim 1024
#define Ntok (Fdim * Pdim)   // 18432
#define KSPLIT 16            // k-chunks for small GEMMs
#define NBLK 512             // persistent grid (2 blocks/CU, co-resident)

// convert 8 consecutive f32 at p (16B-aligned) to a bf16x8 fragment
__device__ __forceinline__ bf16x8 cvt8(const float* __restrict__ p) {
    float4 lo = *(const float4*)p;
    float4 hi = *(const float4*)(p + 4);
    bf16x8 r;
    r[0] = (bf16_t)lo.x; r[1] = (bf16_t)lo.y; r[2] = (bf16_t)lo.z; r[3] = (bf16_t)lo.w;
    r[4] = (bf16_t)hi.x; r[5] = (bf16_t)hi.y; r[6] = (bf16_t)hi.z; r[7] = (bf16_t)hi.w;
    return r;
}

// device-scope grid barrier: one counter per phase (no sense reversal needed)
__device__ __forceinline__ void gridbar(int* cnt, int phase) {
    __syncthreads();
    if (threadIdx.x == 0) {
        __threadfence();                         // release our global writes
        atomicAdd(&cnt[phase], 1);               // device-scope by default
        while (__hip_atomic_load(&cnt[phase], __ATOMIC_RELAXED,
                                 __HIP_MEMORY_SCOPE_AGENT) < NBLK)
            __builtin_amdgcn_s_sleep(8);
        __threadfence();                         // acquire others' writes
    }
    __syncthreads();
}

// splitk unit: parts[ky][64][2048] = Am[64, kchunk] @ Bm[kchunk, 2048]
// (n0, kb) from block id; 4 waves partition M=64; fully unrolled k-chunk of 128.
template <bool A_IS_F32>
__device__ __forceinline__ void splitk_body(
    const void* __restrict__ Am, const float* __restrict__ Bm,
    float* __restrict__ dst, int n0, int kb,
    int wave, int l15, int koct)
{
    f32x4 acc[4] = {};

    #pragma unroll
    for (int i = 0; i < 4; ++i) {
        const int k0 = kb + i * 32;
        bf16x8 a;
        if constexpr (A_IS_F32)
            a = cvt8((const float*)Am + (size_t)(wave * 16 + l15) * Edim + k0 + koct * 8);
        else
            a = *(const bf16x8*)((const bf16_t*)Am + (size_t)(wave * 16 + l15) * Edim + k0 + koct * 8);
        #pragma unroll
        for (int t = 0; t < 4; ++t) {
            const float* src = Bm + (size_t)(k0 + koct * 8) * Edim + n0 + t * 16 + l15;
            bf16x8 b;
            #pragma unroll
            for (int j = 0; j < 8; ++j) b[j] = (bf16_t)src[(size_t)j * Edim];
            acc[t] = __builtin_amdgcn_mfma_f32_16x16x32_bf16(a, b, acc[t], 0, 0, 0);
        }
    }

    #pragma unroll
    for (int t = 0; t < 4; ++t) {
        #pragma unroll
        for (int r = 0; r < 4; ++r) {
            int m = wave * 16 + koct * 4 + r;   // C/D row = (lane>>4)*4 + reg
            int n = n0 + t * 16 + l15;          // C/D col = lane&15
            dst[(size_t)m * Edim + n] = acc[t][r];
        }
    }
}

// ---------------------------------------------------------------------------
// The whole pipeline in one persistent kernel (512 blocks x 256 threads):
//  A: parts1 = splitk(Wmp_bf? no: f32 Wmp @ Wo)            [512 units]
//  B: A_bf = bf16(sum parts1); beff += 0.75*(A.bv + Wmp.bo) [distributed]
//  C: parts2 = splitk(A_bf @ Wv)                            [512 units]
//  D: Weffb = bf16(0.75 * sum parts2)                       [distributed]
//  E: out = X @ Weffb^T + beff (+ row permutation)          [576 tiles]
// ---------------------------------------------------------------------------
__global__ __launch_bounds__(256, 2) void fused_kernel(
    const float* __restrict__ X,
    const float* __restrict__ Wv,  const float* __restrict__ bv,
    const float* __restrict__ Wo,  const float* __restrict__ bo,
    const float* __restrict__ Wmp, const float* __restrict__ bmp,
    int* __restrict__ cnt, float* __restrict__ beff,
    float* __restrict__ parts1, float* __restrict__ parts2,
    bf16_t* __restrict__ A_bf, bf16_t* __restrict__ Weffb,
    float* __restrict__ out)
{
    __shared__ float red[4 * 64 * 33];   // phase E reduce buffer (33.8 KB)

    const int b    = blockIdx.x;
    const int tid  = threadIdx.x;
    const int wave = tid >> 6;
    const int lane = tid & 63;
    const int l15  = lane & 15;
    const int koct = lane >> 4;

    // ---- Phase A: parts1[ky] = Wmp(f32) @ Wo k-chunk ----
    {
        const int n0 = (b & 31) * 64;
        const int kb = (b >> 5) * 128;
        splitk_body<true>(Wmp, Wo, parts1 + (size_t)(b >> 5) * (Cdim * Edim),
                          n0, kb, wave, l15, koct);
    }
    gridbar(cnt, 0);

    // ---- Phase B: reduce parts1 -> A_bf; beff = 0.75*(A.bv + Wmp.bo) + bmp ----
    {
        const int c    = b >> 3;             // 0..63
        const int col0 = (b & 7) * 256;      // 8 chunks of 256 cols
        const int col  = col0 + tid;         // one f32 column per thread

        float a = 0.f;
        #pragma unroll
        for (int j = 0; j < KSPLIT; ++j)
            a += parts1[(size_t)j * (Cdim * Edim) + (size_t)c * Edim + col];

        A_bf[(size_t)c * Edim + col] = (bf16_t)a;

        float s = a * bv[col] + Wmp[(size_t)c * Edim + col] * bo[col];
        #pragma unroll
        for (int off = 32; off > 0; off >>= 1) s += __shfl_down(s, off);
        if (lane == 0) atomicAdd(&beff[c], 0.75f * s);
        if ((b & 7) == 0 && tid == 0) atomicAdd(&beff[c], bmp[c]);
    }
    gridbar(cnt, 1);

    // ---- Phase C: parts2[ky] = A_bf(bf16) @ Wv k-chunk ----
    {
        const int n0 = (b & 31) * 64;
        const int kb = (b >> 5) * 128;
        splitk_body<false>(A_bf, Wv, parts2 + (size_t)(b >> 5) * (Cdim * Edim),
                           n0, kb, wave, l15, koct);
    }
    gridbar(cnt, 2);

    // ---- Phase D: Weffb = bf16(0.75 * sum parts2) ----
    {
        const int i = b * 256 + tid;         // 512*256 = 131072 elems exactly
        float s = 0.f;
        #pragma unroll
        for (int j = 0; j < KSPLIT; ++j)
            s += parts2[(size_t)j * (Cdim * Edim) + i];
        Weffb[i] = (bf16_t)(0.75f * s);
    }
    gridbar(cnt, 3);

    // ---- Phase E: main GEMM over 576 M-tiles (grid-strided) ----
    for (int tile = b; tile < Ntok / 32; tile += NBLK) {
        const int rbase = tile * 32;
        const float* x0 = X + (size_t)(rbase + l15) * Edim;
        const float* x1 = x0 + (size_t)16 * Edim;
        const int kbase = wave * 512;

        f32x4 acc[2][4] = {};

        #pragma unroll 4
        for (int k0 = kbase; k0 < kbase + 512; k0 += 32) {
            bf16x8 a0 = cvt8(x0 + k0 + koct * 8);
            bf16x8 a1 = cvt8(x1 + k0 + koct * 8);
            #pragma unroll
            for (int t = 0; t < 4; ++t) {
                bf16x8 bfr = *(const bf16x8*)(Weffb + (size_t)(t * 16 + l15) * Edim + k0 + koct * 8);
                acc[0][t] = __builtin_amdgcn_mfma_f32_16x16x32_bf16(a0, bfr, acc[0][t], 0, 0, 0);
                acc[1][t] = __builtin_amdgcn_mfma_f32_16x16x32_bf16(a1, bfr, acc[1][t], 0, 0, 0);
            }
        }

        __syncthreads();   // LDS safe vs previous tile's epilogue reads
        {
            float* dst = &red[wave * 2112 + lane * 33];
            #pragma unroll
            for (int e = 0; e < 2; ++e)
                #pragma unroll
                for (int t = 0; t < 4; ++t)
                    #pragma unroll
                    for (int r = 0; r < 4; ++r) dst[e * 16 + t * 4 + r] = acc[e][t][r];
        }
        __syncthreads();

        // wave w reduces the 4 k-quarters and stores column-tile t = w
        {
            const int c  = wave * 16 + l15;
            const float be = beff[c];
            #pragma unroll
            for (int e = 0; e < 2; ++e) {
                #pragma unroll
                for (int r = 0; r < 4; ++r) {
                    float v = 0.f;
                    #pragma unroll
                    for (int ws = 0; ws < 4; ++ws)
                        v += red[ws * 2112 + lane * 33 + e * 16 + wave * 4 + r];
                    const int m = rbase + e * 16 + koct * 4 + r;
                    const int f = m >> 10;          // n / 1024
                    const int p = m & 1023;         // n % 1024
                    out[(size_t)(p * Fdim + f) * Cdim + c] = v + be;
                }
            }
        }
    }
}

// ---------------------------------------------------------------------------
extern "C" void kernel_launch(void* const* d_in, const int* in_sizes, int n_in,
                              void* d_out, int out_size, void* d_ws, size_t ws_size,
                              hipStream_t stream)
{
    // setup_inputs order: emb, Wq, Wk, Wv, bq, bk, bv, Wo, bo, Wmp, bmp (all f32)
    const float* emb = (const float*)d_in[0];
    const float* Wv  = (const float*)d_in[3];
    const float* bv  = (const float*)d_in[6];
    const float* Wo  = (const float*)d_in[7];
    const float* bo  = (const float*)d_in[8];
    const float* Wmp = (const float*)d_in[9];
    const float* bmp = (const float*)d_in[10];

    const size_t PART = (size_t)Cdim * Edim;                     // 131072
    uint8_t* base  = (uint8_t*)d_ws;
    int*    cnt    = (int*)base;                                 // 4 counters
    float*  beff   = (float*)(base + 64);                        // [64] f32
    float*  parts1 = (float*)(base + 1024);                      // [16][64][2048] f32 (8 MB)
    float*  parts2 = parts1 + (size_t)KSPLIT * PART;             // 8 MB
    bf16_t* A_bf   = (bf16_t*)(parts2 + (size_t)KSPLIT * PART);  // [64,2048] bf16
    bf16_t* Weffb  = A_bf + PART;                                // [64,2048] bf16

    float* out = (float*)d_out;

    // zero barrier counters + beff accumulator
    hipMemsetAsync(base, 0, 1024, stream);

    fused_kernel<<<NBLK, 256, 0, stream>>>(
        emb, Wv, bv, Wo, bo, Wmp, bmp,
        cnt, beff, parts1, parts2, A_bf, Weffb, out);
}

// Round 8
// 304.134 us; speedup vs baseline: 1.6500x; 1.6500x over previous
//
#include <hip/hip_runtime.h>
#include <hip/hip_bf16.h>
#include <stdint.h>

typedef __bf16 bf16_t;
typedef __bf16 bf16x8 __attribute__((ext_vector_type(8)));
typedef __bf16 bf16x4 __attribute__((ext_vector_type(4)));
typedef float f32x4 __attribute__((ext_vector_type(4)));

#define Edim 2048
#define Cdim 64
#define Fdim 18
#define Pdim 1024
#define Ntok (Fdim * Pdim)   // 18432
#define KSPLIT 16            // k-chunks for small GEMMs

// convert 8 consecutive f32 at p (16B-aligned) to a bf16x8 fragment
__device__ __forceinline__ bf16x8 cvt8(const float* __restrict__ p) {
    float4 lo = *(const float4*)p;
    float4 hi = *(const float4*)(p + 4);
    bf16x8 r;
    r[0] = (bf16_t)lo.x; r[1] = (bf16_t)lo.y; r[2] = (bf16_t)lo.z; r[3] = (bf16_t)lo.w;
    r[4] = (bf16_t)hi.x; r[5] = (bf16_t)hi.y; r[6] = (bf16_t)hi.z; r[7] = (bf16_t)hi.w;
    return r;
}

// convert two f32x4 registers to a bf16x8 fragment
__device__ __forceinline__ bf16x8 cvt8r(f32x4 lo, f32x4 hi) {
    bf16x8 r;
    r[0] = (bf16_t)lo[0]; r[1] = (bf16_t)lo[1]; r[2] = (bf16_t)lo[2]; r[3] = (bf16_t)lo[3];
    r[4] = (bf16_t)hi[0]; r[5] = (bf16_t)hi[1]; r[6] = (bf16_t)hi[2]; r[7] = (bf16_t)hi[3];
    return r;
}

// ---------------------------------------------------------------------------
// split-K small GEMM: parts[ky][64][2048] = Am[64, kchunk] @ Bm[kchunk, 2048]
// grid = (32 n-tiles, 16 k-chunks of 128), block = 256 (4 waves partition M=64).
// Fully unrolled -> 128 independent B-loads in flight per lane.
// ---------------------------------------------------------------------------
template <bool A_IS_F32>
__global__ __launch_bounds__(256) void splitk_gemm_kernel(
    const void* __restrict__ Am, const float* __restrict__ Bm,
    float* __restrict__ parts)
{
    const int tid  = threadIdx.x;
    const int wave = tid >> 6;
    const int lane = tid & 63;
    const int l15  = lane & 15;
    const int koct = lane >> 4;
    const int n0   = blockIdx.x * 64;
    const int kb   = blockIdx.y * 128;

    f32x4 acc[4] = {};

    #pragma unroll
    for (int i = 0; i < 4; ++i) {
        const int k0 = kb + i * 32;
        bf16x8 a;
        if constexpr (A_IS_F32)
            a = cvt8((const float*)Am + (size_t)(wave * 16 + l15) * Edim + k0 + koct * 8);
        else
            a = *(const bf16x8*)((const bf16_t*)Am + (size_t)(wave * 16 + l15) * Edim + k0 + koct * 8);
        #pragma unroll
        for (int t = 0; t < 4; ++t) {
            const float* src = Bm + (size_t)(k0 + koct * 8) * Edim + n0 + t * 16 + l15;
            bf16x8 b;
            #pragma unroll
            for (int j = 0; j < 8; ++j) b[j] = (bf16_t)src[(size_t)j * Edim];
            acc[t] = __builtin_amdgcn_mfma_f32_16x16x32_bf16(a, b, acc[t], 0, 0, 0);
        }
    }

    float* dst = parts + (size_t)blockIdx.y * (Cdim * Edim);
    #pragma unroll
    for (int t = 0; t < 4; ++t) {
        #pragma unroll
        for (int r = 0; r < 4; ++r) {
            int m = wave * 16 + koct * 4 + r;   // C/D row = (lane>>4)*4 + reg
            int n = n0 + t * 16 + l15;          // C/D col = lane&15
            dst[(size_t)m * Edim + n] = acc[t][r];
        }
    }
}

// ---------------------------------------------------------------------------
// Fused reduce + bias. grid = 64 (one block per row c), block = 256.
// A_bf[c,:] = bf16(sum_j parts[j][c][:]);
// beff[c] = 0.75*( A_f32[c,:]·bv + Wmp[c,:]·bo ) + bmp[c].
// ---------------------------------------------------------------------------
__global__ __launch_bounds__(256) void reduce_bias_kernel(
    const float* __restrict__ parts, const float* __restrict__ Wmp,
    const float* __restrict__ bv, const float* __restrict__ bo,
    const float* __restrict__ bmp,
    bf16_t* __restrict__ A_bf, float* __restrict__ beff)
{
    const int c   = blockIdx.x;
    const int tid = threadIdx.x;
    const int col = tid * 8;

    float4 s0 = {0.f, 0.f, 0.f, 0.f}, s1 = {0.f, 0.f, 0.f, 0.f};
    #pragma unroll
    for (int j = 0; j < KSPLIT; ++j) {
        const float* p = parts + (size_t)j * (Cdim * Edim) + (size_t)c * Edim + col;
        float4 v0 = *(const float4*)p;
        float4 v1 = *(const float4*)(p + 4);
        s0.x += v0.x; s0.y += v0.y; s0.z += v0.z; s0.w += v0.w;
        s1.x += v1.x; s1.y += v1.y; s1.z += v1.z; s1.w += v1.w;
    }

    bf16x8 r;
    r[0] = (bf16_t)s0.x; r[1] = (bf16_t)s0.y; r[2] = (bf16_t)s0.z; r[3] = (bf16_t)s0.w;
    r[4] = (bf16_t)s1.x; r[5] = (bf16_t)s1.y; r[6] = (bf16_t)s1.z; r[7] = (bf16_t)s1.w;
    *(bf16x8*)(A_bf + (size_t)c * Edim + col) = r;

    float4 b0 = *(const float4*)(bv + col);
    float4 b1 = *(const float4*)(bv + col + 4);
    float4 w0 = *(const float4*)(Wmp + (size_t)c * Edim + col);
    float4 w1 = *(const float4*)(Wmp + (size_t)c * Edim + col + 4);
    float4 o0 = *(const float4*)(bo + col);
    float4 o1 = *(const float4*)(bo + col + 4);

    float s = s0.x * b0.x + s0.y * b0.y + s0.z * b0.z + s0.w * b0.w
            + s1.x * b1.x + s1.y * b1.y + s1.z * b1.z + s1.w * b1.w
            + w0.x * o0.x + w0.y * o0.y + w0.z * o0.z + w0.w * o0.w
            + w1.x * o1.x + w1.y * o1.y + w1.z * o1.z + w1.w * o1.w;

    #pragma unroll
    for (int off = 32; off > 0; off >>= 1) s += __shfl_down(s, off);

    __shared__ float red[4];
    if ((tid & 63) == 0) red[tid >> 6] = s;
    __syncthreads();
    if (tid == 0)
        beff[c] = 0.75f * (red[0] + red[1] + red[2] + red[3]) + bmp[c];
}

// ---------------------------------------------------------------------------
// out_bf16[i] = scale * sum_{j<16} parts[j][i]   (131072 elems; grid 128 x 256)
// ---------------------------------------------------------------------------
__global__ __launch_bounds__(256) void reduce_parts_kernel(
    const float* __restrict__ parts, bf16_t* __restrict__ out, float scale)
{
    const int idx = (blockIdx.x * 256 + threadIdx.x) * 4;
    float4 s = {0.f, 0.f, 0.f, 0.f};
    #pragma unroll
    for (int j = 0; j < KSPLIT; ++j) {
        float4 v = *(const float4*)(parts + (size_t)j * (Cdim * Edim) + idx);
        s.x += v.x; s.y += v.y; s.z += v.z; s.w += v.w;
    }
    bf16x4 r;
    r[0] = (bf16_t)(scale * s.x); r[1] = (bf16_t)(scale * s.y);
    r[2] = (bf16_t)(scale * s.z); r[3] = (bf16_t)(scale * s.w);
    *(bf16x4*)(out + idx) = r;
}

// ---------------------------------------------------------------------------
// main GEMM: out[(p*F+f)*64+c] = X[n,:]·Weff[c,:] + b_eff[c],  n = f*P+p
// grid = 1152 (M=16 rows/block), block = 256, split-K x4 across waves
// (4608 waves ~ 18/CU). Explicit register double-buffer on the X fragment
// (peeled prologue + rotated loop) keeps loads in flight every cycle.
// All-wave LDS reduce epilogue: wave w stores column-tile t=w.
// ---------------------------------------------------------------------------
__global__ __launch_bounds__(256, 4) void main_gemm_kernel(
    const float* __restrict__ X, const bf16_t* __restrict__ Weff,
    const float* __restrict__ b_eff, float* __restrict__ out)
{
    __shared__ float red[4 * 64 * 17];   // 4 waves x 64 lanes x 16 vals (+1 pad)

    const int tid  = threadIdx.x;
    const int wave = tid >> 6;
    const int lane = tid & 63;
    const int l15  = lane & 15;
    const int koct = lane >> 4;

    const int rbase = blockIdx.x * 16;
    const float* xp = X + (size_t)(rbase + l15) * Edim + koct * 8;  // per-lane base
    const int kbase = wave * 512;

    f32x4 acc[4] = {};

    // prologue: first X fragment in flight
    f32x4 pa = *(const f32x4*)(xp + kbase);
    f32x4 pb = *(const f32x4*)(xp + kbase + 4);

    #pragma unroll 5
    for (int i = 0; i < 15; ++i) {
        const int k0 = kbase + i * 32;
        // next-iter X fragment: issue before consuming current
        f32x4 na = *(const f32x4*)(xp + k0 + 32);
        f32x4 nb = *(const f32x4*)(xp + k0 + 36);
        bf16x8 a = cvt8r(pa, pb);
        #pragma unroll
        for (int t = 0; t < 4; ++t) {
            bf16x8 b = *(const bf16x8*)(Weff + (size_t)(t * 16 + l15) * Edim + k0 + koct * 8);
            acc[t] = __builtin_amdgcn_mfma_f32_16x16x32_bf16(a, b, acc[t], 0, 0, 0);
        }
        pa = na; pb = nb;
    }
    {   // final iteration
        const int k0 = kbase + 480;
        bf16x8 a = cvt8r(pa, pb);
        #pragma unroll
        for (int t = 0; t < 4; ++t) {
            bf16x8 b = *(const bf16x8*)(Weff + (size_t)(t * 16 + l15) * Edim + k0 + koct * 8);
            acc[t] = __builtin_amdgcn_mfma_f32_16x16x32_bf16(a, b, acc[t], 0, 0, 0);
        }
    }

    // all waves dump accumulators to LDS
    {
        float* dst = &red[wave * 1088 + lane * 17];
        #pragma unroll
        for (int t = 0; t < 4; ++t)
            #pragma unroll
            for (int r = 0; r < 4; ++r) dst[t * 4 + r] = acc[t][r];
    }
    __syncthreads();

    // wave w sums the 4 k-quarters for column-tile t = w and stores
    {
        const int c  = wave * 16 + l15;
        const float be = b_eff[c];
        #pragma unroll
        for (int r = 0; r < 4; ++r) {
            float v = 0.f;
            #pragma unroll
            for (int ws = 0; ws < 4; ++ws)
                v += red[ws * 1088 + lane * 17 + wave * 4 + r];
            const int m = rbase + koct * 4 + r;
            const int f = m >> 10;          // n / 1024
            const int p = m & 1023;         // n % 1024
            out[(size_t)(p * Fdim + f) * Cdim + c] = v + be;
        }
    }
}

// ---------------------------------------------------------------------------
extern "C" void kernel_launch(void* const* d_in, const int* in_sizes, int n_in,
                              void* d_out, int out_size, void* d_ws, size_t ws_size,
                              hipStream_t stream)
{
    // setup_inputs order: emb, Wq, Wk, Wv, bq, bk, bv, Wo, bo, Wmp, bmp (all f32)
    const float* emb = (const float*)d_in[0];
    const float* Wv  = (const float*)d_in[3];
    const float* bv  = (const float*)d_in[6];
    const float* Wo  = (const float*)d_in[7];
    const float* bo  = (const float*)d_in[8];
    const float* Wmp = (const float*)d_in[9];
    const float* bmp = (const float*)d_in[10];

    const size_t PART = (size_t)Cdim * Edim;                     // 131072
    float*  parts1 = (float*)d_ws;                               // [16][64][2048] f32 (8 MB)
    float*  parts2 = parts1 + (size_t)KSPLIT * PART;             // 8 MB
    bf16_t* A_bf   = (bf16_t*)(parts2 + (size_t)KSPLIT * PART);  // [64,2048] bf16
    bf16_t* Weffb  = A_bf + PART;                                // [64,2048] bf16
    float*  beff   = (float*)(Weffb + PART);                     // [64] f32

    float* out = (float*)d_out;

    // A partials = Wmp @ Wo (split-K x16)
    splitk_gemm_kernel<true><<<dim3(32, KSPLIT), 256, 0, stream>>>(Wmp, Wo, parts1);
    // A_bf = bf16(sum parts1); beff = 0.75*(A·bv + Wmp·bo) + bmp
    reduce_bias_kernel<<<64, 256, 0, stream>>>(parts1, Wmp, bv, bo, bmp, A_bf, beff);
    // Weff partials = A @ Wv (split-K x16)
    splitk_gemm_kernel<false><<<dim3(32, KSPLIT), 256, 0, stream>>>(A_bf, Wv, parts2);
    // Weffb = bf16(0.75 * sum parts2)
    reduce_parts_kernel<<<128, 256, 0, stream>>>(parts2, Weffb, 0.75f);
    // out = X @ Weff^T + b_eff  (+ output row permutation)
    main_gemm_kernel<<<Ntok / 16, 256, 0, stream>>>(emb, Weffb, beff, out);
}

// Round 9
// 290.197 us; speedup vs baseline: 1.7293x; 1.0480x over previous
//
#include <hip/hip_runtime.h>
#include <hip/hip_bf16.h>
#include <stdint.h>

typedef __bf16 bf16_t;
typedef __bf16 bf16x8 __attribute__((ext_vector_type(8)));
typedef __bf16 bf16x4 __attribute__((ext_vector_type(4)));
typedef float f32x4 __attribute__((ext_vector_type(4)));

#define Edim 2048
#define Cdim 64
#define Fdim 18
#define Pdim 1024
#define Ntok (Fdim * Pdim)   // 18432
#define KSPLIT 16            // k-chunks for small GEMMs

#define BM 32                // rows per block (main GEMM)
#define BK 256               // K-chunk staged per iteration
#define NCHUNK (Edim / BK)   // 8
#define XSTRIDE 260          // f32 words per LDS row (+4 pad: 16B-aligned rows,
                             // uniform bank spread for b128 fragment reads)

// convert 8 consecutive f32 at p (16B-aligned) to a bf16x8 fragment
__device__ __forceinline__ bf16x8 cvt8(const float* __restrict__ p) {
    float4 lo = *(const float4*)p;
    float4 hi = *(const float4*)(p + 4);
    bf16x8 r;
    r[0] = (bf16_t)lo.x; r[1] = (bf16_t)lo.y; r[2] = (bf16_t)lo.z; r[3] = (bf16_t)lo.w;
    r[4] = (bf16_t)hi.x; r[5] = (bf16_t)hi.y; r[6] = (bf16_t)hi.z; r[7] = (bf16_t)hi.w;
    return r;
}

// convert two f32x4 registers to a bf16x8 fragment
__device__ __forceinline__ bf16x8 cvt8r(f32x4 lo, f32x4 hi) {
    bf16x8 r;
    r[0] = (bf16_t)lo[0]; r[1] = (bf16_t)lo[1]; r[2] = (bf16_t)lo[2]; r[3] = (bf16_t)lo[3];
    r[4] = (bf16_t)hi[0]; r[5] = (bf16_t)hi[1]; r[6] = (bf16_t)hi[2]; r[7] = (bf16_t)hi[3];
    return r;
}

// ---------------------------------------------------------------------------
// split-K small GEMM: parts[ky][64][2048] = Am[64, kchunk] @ Bm[kchunk, 2048]
// grid = (32 n-tiles, 16 k-chunks of 128), block = 256 (4 waves partition M=64).
// Fully unrolled -> 128 independent B-loads in flight per lane.
// ---------------------------------------------------------------------------
template <bool A_IS_F32>
__global__ __launch_bounds__(256) void splitk_gemm_kernel(
    const void* __restrict__ Am, const float* __restrict__ Bm,
    float* __restrict__ parts)
{
    const int tid  = threadIdx.x;
    const int wave = tid >> 6;
    const int lane = tid & 63;
    const int l15  = lane & 15;
    const int koct = lane >> 4;
    const int n0   = blockIdx.x * 64;
    const int kb   = blockIdx.y * 128;

    f32x4 acc[4] = {};

    #pragma unroll
    for (int i = 0; i < 4; ++i) {
        const int k0 = kb + i * 32;
        bf16x8 a;
        if constexpr (A_IS_F32)
            a = cvt8((const float*)Am + (size_t)(wave * 16 + l15) * Edim + k0 + koct * 8);
        else
            a = *(const bf16x8*)((const bf16_t*)Am + (size_t)(wave * 16 + l15) * Edim + k0 + koct * 8);
        #pragma unroll
        for (int t = 0; t < 4; ++t) {
            const float* src = Bm + (size_t)(k0 + koct * 8) * Edim + n0 + t * 16 + l15;
            bf16x8 b;
            #pragma unroll
            for (int j = 0; j < 8; ++j) b[j] = (bf16_t)src[(size_t)j * Edim];
            acc[t] = __builtin_amdgcn_mfma_f32_16x16x32_bf16(a, b, acc[t], 0, 0, 0);
        }
    }

    float* dst = parts + (size_t)blockIdx.y * (Cdim * Edim);
    #pragma unroll
    for (int t = 0; t < 4; ++t) {
        #pragma unroll
        for (int r = 0; r < 4; ++r) {
            int m = wave * 16 + koct * 4 + r;   // C/D row = (lane>>4)*4 + reg
            int n = n0 + t * 16 + l15;          // C/D col = lane&15
            dst[(size_t)m * Edim + n] = acc[t][r];
        }
    }
}

// ---------------------------------------------------------------------------
// Fused reduce + bias. grid = 64 (one block per row c), block = 256.
// A_bf[c,:] = bf16(sum_j parts[j][c][:]);
// beff[c] = 0.75*( A_f32[c,:]·bv + Wmp[c,:]·bo ) + bmp[c].
// ---------------------------------------------------------------------------
__global__ __launch_bounds__(256) void reduce_bias_kernel(
    const float* __restrict__ parts, const float* __restrict__ Wmp,
    const float* __restrict__ bv, const float* __restrict__ bo,
    const float* __restrict__ bmp,
    bf16_t* __restrict__ A_bf, float* __restrict__ beff)
{
    const int c   = blockIdx.x;
    const int tid = threadIdx.x;
    const int col = tid * 8;

    float4 s0 = {0.f, 0.f, 0.f, 0.f}, s1 = {0.f, 0.f, 0.f, 0.f};
    #pragma unroll
    for (int j = 0; j < KSPLIT; ++j) {
        const float* p = parts + (size_t)j * (Cdim * Edim) + (size_t)c * Edim + col;
        float4 v0 = *(const float4*)p;
        float4 v1 = *(const float4*)(p + 4);
        s0.x += v0.x; s0.y += v0.y; s0.z += v0.z; s0.w += v0.w;
        s1.x += v1.x; s1.y += v1.y; s1.z += v1.z; s1.w += v1.w;
    }

    bf16x8 r;
    r[0] = (bf16_t)s0.x; r[1] = (bf16_t)s0.y; r[2] = (bf16_t)s0.z; r[3] = (bf16_t)s0.w;
    r[4] = (bf16_t)s1.x; r[5] = (bf16_t)s1.y; r[6] = (bf16_t)s1.z; r[7] = (bf16_t)s1.w;
    *(bf16x8*)(A_bf + (size_t)c * Edim + col) = r;

    float4 b0 = *(const float4*)(bv + col);
    float4 b1 = *(const float4*)(bv + col + 4);
    float4 w0 = *(const float4*)(Wmp + (size_t)c * Edim + col);
    float4 w1 = *(const float4*)(Wmp + (size_t)c * Edim + col + 4);
    float4 o0 = *(const float4*)(bo + col);
    float4 o1 = *(const float4*)(bo + col + 4);

    float s = s0.x * b0.x + s0.y * b0.y + s0.z * b0.z + s0.w * b0.w
            + s1.x * b1.x + s1.y * b1.y + s1.z * b1.z + s1.w * b1.w
            + w0.x * o0.x + w0.y * o0.y + w0.z * o0.z + w0.w * o0.w
            + w1.x * o1.x + w1.y * o1.y + w1.z * o1.z + w1.w * o1.w;

    #pragma unroll
    for (int off = 32; off > 0; off >>= 1) s += __shfl_down(s, off);

    __shared__ float red[4];
    if ((tid & 63) == 0) red[tid >> 6] = s;
    __syncthreads();
    if (tid == 0)
        beff[c] = 0.75f * (red[0] + red[1] + red[2] + red[3]) + bmp[c];
}

// ---------------------------------------------------------------------------
// out_bf16[i] = scale * sum_{j<16} parts[j][i]   (131072 elems; grid 128 x 256)
// ---------------------------------------------------------------------------
__global__ __launch_bounds__(256) void reduce_parts_kernel(
    const float* __restrict__ parts, bf16_t* __restrict__ out, float scale)
{
    const int idx = (blockIdx.x * 256 + threadIdx.x) * 4;
    float4 s = {0.f, 0.f, 0.f, 0.f};
    #pragma unroll
    for (int j = 0; j < KSPLIT; ++j) {
        float4 v = *(const float4*)(parts + (size_t)j * (Cdim * Edim) + idx);
        s.x += v.x; s.y += v.y; s.z += v.z; s.w += v.w;
    }
    bf16x4 r;
    r[0] = (bf16_t)(scale * s.x); r[1] = (bf16_t)(scale * s.y);
    r[2] = (bf16_t)(scale * s.z); r[3] = (bf16_t)(scale * s.w);
    *(bf16x4*)(out + idx) = r;
}

// ---------------------------------------------------------------------------
// main GEMM (m97-style): out[(p*F+f)*64+c] = X[n,:]·Weff[c,:] + beff[c]
// grid = 576 (BM=32 rows/block), block = 256 (4 waves).
// Per K-chunk (BK=256): async global_load_lds stages the 32x256 f32 X-tile
// (8 x 1KB instructions per wave, all in flight), barrier, then MFMA from LDS.
// Waves split C: wave w owns output cols w*16..w*16+15 (B-frag = Weff row
// w*16+l15) over ALL 32 rows -> no cross-wave reduce; direct stores.
// ---------------------------------------------------------------------------
__global__ __launch_bounds__(256, 2) void main_gemm_kernel(
    const float* __restrict__ X, const bf16_t* __restrict__ Weff,
    const float* __restrict__ b_eff, float* __restrict__ out)
{
    __shared__ __align__(16) float xs[BM * XSTRIDE];   // 33280 B

    const int tid  = threadIdx.x;
    const int wave = tid >> 6;
    const int lane = tid & 63;
    const int l15  = lane & 15;
    const int koct = lane >> 4;

    const int rbase = blockIdx.x * BM;
    const int c     = wave * 16 + l15;                 // this wave's output col
    const bf16_t* wrow = Weff + (size_t)c * Edim;      // B-frag row (row index = c)

    f32x4 acc0 = {}, acc1 = {};

    for (int kc = 0; kc < NCHUNK; ++kc) {
        if (kc) __syncthreads();   // previous chunk's LDS reads done

        // stage: wave w loads rows w*8 .. w*8+7 (1 KB per row = one instruction)
        #pragma unroll
        for (int i = 0; i < 8; ++i) {
            const int r = wave * 8 + i;
            const float* gsrc = X + (size_t)(rbase + r) * Edim + kc * BK + lane * 4;
            __builtin_amdgcn_global_load_lds(
                (const __attribute__((address_space(1))) void*)gsrc,
                (__attribute__((address_space(3))) void*)&xs[r * XSTRIDE],
                16, 0, 0);
        }
        __syncthreads();           // drains vmcnt (staging complete)

        #pragma unroll
        for (int ks = 0; ks < BK; ks += 32) {
            const float* a0p = &xs[l15 * XSTRIDE + ks + koct * 8];
            const float* a1p = a0p + 16 * XSTRIDE;
            bf16x8 a0 = cvt8r(*(const f32x4*)a0p, *(const f32x4*)(a0p + 4));
            bf16x8 a1 = cvt8r(*(const f32x4*)a1p, *(const f32x4*)(a1p + 4));
            bf16x8 b  = *(const bf16x8*)(wrow + kc * BK + ks + koct * 8);
            acc0 = __builtin_amdgcn_mfma_f32_16x16x32_bf16(a0, b, acc0, 0, 0, 0);
            acc1 = __builtin_amdgcn_mfma_f32_16x16x32_bf16(a1, b, acc1, 0, 0, 0);
        }
    }

    // epilogue: direct stores (C/D: col = lane&15 -> c; row = koct*4 + reg)
    const float be = b_eff[c];
    #pragma unroll
    for (int e = 0; e < 2; ++e) {
        f32x4 a = e ? acc1 : acc0;
        #pragma unroll
        for (int r = 0; r < 4; ++r) {
            const int m = rbase + e * 16 + koct * 4 + r;
            const int f = m >> 10;          // n / 1024
            const int p = m & 1023;         // n % 1024
            out[(size_t)(p * Fdim + f) * Cdim + c] = a[r] + be;
        }
    }
}

// ---------------------------------------------------------------------------
extern "C" void kernel_launch(void* const* d_in, const int* in_sizes, int n_in,
                              void* d_out, int out_size, void* d_ws, size_t ws_size,
                              hipStream_t stream)
{
    // setup_inputs order: emb, Wq, Wk, Wv, bq, bk, bv, Wo, bo, Wmp, bmp (all f32)
    const float* emb = (const float*)d_in[0];
    const float* Wv  = (const float*)d_in[3];
    const float* bv  = (const float*)d_in[6];
    const float* Wo  = (const float*)d_in[7];
    const float* bo  = (const float*)d_in[8];
    const float* Wmp = (const float*)d_in[9];
    const float* bmp = (const float*)d_in[10];

    const size_t PART = (size_t)Cdim * Edim;                     // 131072
    float*  parts1 = (float*)d_ws;                               // [16][64][2048] f32 (8 MB)
    float*  parts2 = parts1 + (size_t)KSPLIT * PART;             // 8 MB
    bf16_t* A_bf   = (bf16_t*)(parts2 + (size_t)KSPLIT * PART);  // [64,2048] bf16
    bf16_t* Weffb  = A_bf + PART;                                // [64,2048] bf16
    float*  beff   = (float*)(Weffb + PART);                     // [64] f32

    float* out = (float*)d_out;

    // A partials = Wmp @ Wo (split-K x16)
    splitk_gemm_kernel<true><<<dim3(32, KSPLIT), 256, 0, stream>>>(Wmp, Wo, parts1);
    // A_bf = bf16(sum parts1); beff = 0.75*(A·bv + Wmp·bo) + bmp
    reduce_bias_kernel<<<64, 256, 0, stream>>>(parts1, Wmp, bv, bo, bmp, A_bf, beff);
    // Weff partials = A @ Wv (split-K x16)
    splitk_gemm_kernel<false><<<dim3(32, KSPLIT), 256, 0, stream>>>(A_bf, Wv, parts2);
    // Weffb = bf16(0.75 * sum parts2)
    reduce_parts_kernel<<<128, 256, 0, stream>>>(parts2, Weffb, 0.75f);
    // out = X @ Weff^T + beff  (+ output row permutation)
    main_gemm_kernel<<<Ntok / BM, 256, 0, stream>>>(emb, Weffb, beff, out);
}